// Round 1
// baseline (69.010 us; speedup 1.0000x reference)
//
#include <hip/hip_runtime.h>

#define LPTS 4096
#define NTOKS 512
#define TILE 128
#define NT (LPTS / TILE)                 // 32
#define NPAIRTILES (NT * (NT + 1) / 2)   // 528

// ws layout:
//   float idx [0..3]  mse_sum[4]
//   float idx [4]     mask_sum
//   float idx [5..8]  s_sum[4]
//   float idx [9]     pm_sum
//   int   idx [10..14] format flags (0:tok_odd_nonzero, 1:crd_bytes, 2:dna_bytes, 3:rna_bytes, 4:lig_bytes)
//   byte 256:  float4 gt4[LPTS]   (gx,gy,gz, meta)
//   +64KB:     float4 px[LPTS]    (x-coord for d=0..3)
//   +128KB:    float4 py[LPTS]
//   +192KB:    float4 pz[LPTS]

static __device__ __forceinline__ float nan0(float x) {
  if (!(x == x)) return 0.f;                       // nan -> 0
  return fminf(fmaxf(x, -3.402823466e38f), 3.402823466e38f);  // +-inf -> +-FLT_MAX
}

// sum of 4 sigmoids: sigmoid(0.5-d)+sigmoid(1-d)+sigmoid(2-d)+sigmoid(4-d)
//  = N(e)/D(e) with e = exp(delta), c_i = exp(-a_i)
//  D = prod(1+c_i e),  N = sum_i prod_{j!=i}(1+c_j e)
static __device__ __forceinline__ float sterm(float dx, float dy, float dz, float tmp) {
  float d2 = fmaf(dx, dx, fmaf(dy, dy, dz * dz));
  float pd = sqrtf(d2);
  float delta = fminf(fabsf(pd + tmp), 25.f);      // clamp: avoids inf/inf, s(25)~1e-9
  float e = __expf(delta);
  float e2 = e * e;
  float e3 = e2 * e;
  float e4 = e2 * e2;
  float Nn = fmaf(0.0366994762f, e3, fmaf(0.7506558488f, e2, fmaf(3.3841830690f, e, 4.f)));
  float Dd = fmaf(0.00055308437f, e4,
             fmaf(0.0366994762f, e3, fmaf(0.3753279244f, e2, fmaf(1.1280610231f, e, 1.f))));
  return Nn * __builtin_amdgcn_rcpf(Dd);
}

__global__ __launch_bounds__(256) void detect_kernel(
    const int* __restrict__ tok, const int* __restrict__ crd,
    const int* __restrict__ dna, const int* __restrict__ rna,
    const int* __restrict__ lig, int* __restrict__ flags) {
  int t = threadIdx.x;
  int f0 = 0;
  for (int i = t; i < LPTS / 2; i += 256)          // odd int32 words of first 2048 int64 slots
    if (tok[2 * i + 1] != 0) f0 = 1;
  if (f0) atomicOr(&flags[0], 1);
  int f1 = 0;
  for (int i = t; i < LPTS / 4; i += 256)          // stay within 4096 bytes (min possible size)
    if ((unsigned)crd[i] > 1u) f1 = 1;
  if (f1) atomicOr(&flags[1], 1);
  int f2 = 0, f3 = 0, f4 = 0;
  for (int i = t; i < NTOKS / 4; i += 256) {
    if ((unsigned)dna[i] > 1u) f2 = 1;
    if ((unsigned)rna[i] > 1u) f3 = 1;
    if ((unsigned)lig[i] > 1u) f4 = 1;
  }
  if (f2) atomicOr(&flags[2], 1);
  if (f3) atomicOr(&flags[3], 1);
  if (f4) atomicOr(&flags[4], 1);
}

__global__ __launch_bounds__(256) void prep_kernel(
    const float* __restrict__ XL, const float* __restrict__ Xgt,
    const void* __restrict__ crd, const void* __restrict__ dna,
    const void* __restrict__ rna, const void* __restrict__ lig,
    const void* __restrict__ tok, float* __restrict__ ws) {
  const int* flags = (const int*)(ws + 10);
  int l = blockIdx.x * 256 + threadIdx.x;
  bool tok64 = (flags[0] == 0);
  bool crdb = flags[1] != 0, dnab = flags[2] != 0, rnab = flags[3] != 0, ligb = flags[4] != 0;
  int tk = tok64 ? ((const int*)tok)[2 * l] : ((const int*)tok)[l];
  int tki = min(max(tk, 0), NTOKS - 1);            // safety clamp for indexing
  int m  = (crdb ? (int)((const unsigned char*)crd)[l]   : ((const int*)crd)[l])   != 0;
  int dn = (dnab ? (int)((const unsigned char*)dna)[tki] : ((const int*)dna)[tki]) != 0;
  int rn = (rnab ? (int)((const unsigned char*)rna)[tki] : ((const int*)rna)[tki]) != 0;
  int lg = (ligb ? (int)((const unsigned char*)lig)[tki] : ((const int*)lig)[tki]) != 0;
  float w = (1.f + 5.f * dn + 5.f * rn + 10.f * lg) * (float)m;
  float gx = nan0(Xgt[3 * l + 0]);
  float gy = nan0(Xgt[3 * l + 1]);
  float gz = nan0(Xgt[3 * l + 2]);
  int isna = dn | rn;
  int meta = (tk & 0xFFFF) | (m << 16) | (isna << 17);
  float4* gt4 = (float4*)((char*)ws + 256);
  float4* px = gt4 + LPTS;
  float4* py = px + LPTS;
  float4* pz = py + LPTS;
  gt4[l] = make_float4(gx, gy, gz, __int_as_float(meta));
  float xs[4], ys[4], zs[4], msum[4];
#pragma unroll
  for (int d = 0; d < 4; ++d) {
    xs[d] = XL[(d * LPTS + l) * 3 + 0];
    ys[d] = XL[(d * LPTS + l) * 3 + 1];
    zs[d] = XL[(d * LPTS + l) * 3 + 2];
    float dx = xs[d] - gx, dy = ys[d] - gy, dz = zs[d] - gz;
    msum[d] = w * (dx * dx + dy * dy + dz * dz);
  }
  px[l] = make_float4(xs[0], xs[1], xs[2], xs[3]);
  py[l] = make_float4(ys[0], ys[1], ys[2], ys[3]);
  pz[l] = make_float4(zs[0], zs[1], zs[2], zs[3]);
  float v[5] = {msum[0], msum[1], msum[2], msum[3], (float)m};
#pragma unroll
  for (int k = 0; k < 5; ++k) {
    float x = v[k];
#pragma unroll
    for (int off = 32; off; off >>= 1) x += __shfl_down(x, off, 64);
    v[k] = x;
  }
  __shared__ float bred[4][5];
  int wid = threadIdx.x >> 6, lane = threadIdx.x & 63;
  if (lane == 0) {
    for (int k = 0; k < 5; ++k) bred[wid][k] = v[k];
  }
  __syncthreads();
  if (threadIdx.x == 0) {
    for (int k = 0; k < 5; ++k) {
      float s = bred[0][k] + bred[1][k] + bred[2][k] + bred[3][k];
      atomicAdd(&ws[k], s);
    }
  }
}

__global__ __launch_bounds__(256) void pair_kernel(float* __restrict__ ws) {
  const float4* gt4 = (const float4*)((const char*)ws + 256);
  const float4* px = gt4 + LPTS;
  const float4* py = px + LPTS;
  const float4* pz = py + LPTS;
  __shared__ float4 sg[TILE], sx[TILE], sy[TILE], sz[TILE];
  // decode triangular tile index (ti <= tj)
  int b = blockIdx.x, ti = 0;
  while (b >= NT - ti) { b -= NT - ti; ++ti; }
  int tj = ti + b;
  int i0 = ti * TILE, j0 = tj * TILE;
  int t = threadIdx.x;
  int r = t & (TILE - 1), h = t >> 7;
  if (t < TILE) {
    sg[t] = gt4[j0 + t];
    sx[t] = px[j0 + t];
    sy[t] = py[j0 + t];
    sz[t] = pz[j0 + t];
  }
  __syncthreads();
  int i = i0 + r;
  float4 rg = gt4[i], rx = px[i], ry = py[i], rz = pz[i];
  int rmeta = __float_as_int(rg.w);
  int rtok = rmeta & 0xFFFF;
  bool rm = (rmeta >> 16) & 1;
  float cutoff = ((rmeta >> 17) & 1) ? 30.f : 15.f;
  float4 accs = make_float4(0.f, 0.f, 0.f, 0.f);
  float accp = 0.f;
  bool diag = (ti == tj);
  for (int jj = h * 64; jj < h * 64 + 64; ++jj) {
    float4 cg = sg[jj];
    int cmeta = __float_as_int(cg.w);
    if (!((cmeta >> 16) & 1)) continue;            // column unmasked: wave-uniform skip
    float dgx = rg.x - cg.x, dgy = rg.y - cg.y, dgz = rg.z - cg.z;
    float gd = sqrtf(fmaf(dgx, dgx, fmaf(dgy, dgy, dgz * dgz)));
    int ctok = cmeta & 0xFFFF;
    bool pm = rm && (gd > 0.f) && (gd < cutoff) && (rtok != ctok);
    if (diag) pm = pm && (j0 + jj > i);
    float pmf = pm ? 1.f : 0.f;
    float tmp = 1e-6f - gd;
    float4 cx = sx[jj], cy = sy[jj], cz = sz[jj];
    float s0 = sterm(rx.x - cx.x, ry.x - cy.x, rz.x - cz.x, tmp);
    float s1 = sterm(rx.y - cx.y, ry.y - cy.y, rz.y - cz.y, tmp);
    float s2 = sterm(rx.z - cx.z, ry.z - cy.z, rz.z - cz.z, tmp);
    float s3 = sterm(rx.w - cx.w, ry.w - cy.w, rz.w - cz.w, tmp);
    accs.x = fmaf(s0, pmf, accs.x);
    accs.y = fmaf(s1, pmf, accs.y);
    accs.z = fmaf(s2, pmf, accs.z);
    accs.w = fmaf(s3, pmf, accs.w);
    accp += pmf;
  }
  float v[5] = {accs.x, accs.y, accs.z, accs.w, accp};
#pragma unroll
  for (int k = 0; k < 5; ++k) {
    float x = v[k];
#pragma unroll
    for (int off = 32; off; off >>= 1) x += __shfl_down(x, off, 64);
    v[k] = x;
  }
  __shared__ float bred[4][5];
  int wid = t >> 6, lane = t & 63;
  if (lane == 0) {
    for (int k = 0; k < 5; ++k) bred[wid][k] = v[k];
  }
  __syncthreads();
  if (t == 0) {
    for (int k = 0; k < 5; ++k) {
      float s = bred[0][k] + bred[1][k] + bred[2][k] + bred[3][k];
      atomicAdd(&ws[k < 4 ? 5 + k : 9], s);
    }
  }
}

__global__ void final_kernel(const float* __restrict__ ws, const float* __restrict__ t,
                             float* __restrict__ out) {
  float mask_sum = ws[4];
  float pm_sum = ws[9];
  float tot = 0.f;
#pragma unroll
  for (int d = 0; d < 4; ++d) {
    float lmse = (ws[d] * (1.f / 3.f)) / (mask_sum + 1e-4f);
    float td = t[d];
    float lam = (td * td + 256.f) / (256.f * td * td);
    float ldiff = fminf(lam * lmse, 2.f);
    float lddt = 0.25f * ws[5 + d] / (pm_sum + 1e-6f);
    tot += 0.25f * (ldiff + (1.f - lddt));
  }
  out[0] = 4.f * tot;
}

extern "C" void kernel_launch(void* const* d_in, const int* in_sizes, int n_in,
                              void* d_out, int out_size, void* d_ws, size_t ws_size,
                              hipStream_t stream) {
  (void)in_sizes; (void)n_in; (void)out_size; (void)ws_size;
  const float* XL  = (const float*)d_in[0];
  const float* Xgt = (const float*)d_in[1];
  const void* crd  = d_in[2];
  const void* dna  = d_in[3];
  const void* rna  = d_in[4];
  const void* lig  = d_in[5];
  const void* tok  = d_in[6];
  const float* t   = (const float*)d_in[7];
  float* ws = (float*)d_ws;
  float* out = (float*)d_out;

  hipMemsetAsync(d_ws, 0, 64, stream);  // zero accumulators + flags every call
  detect_kernel<<<1, 256, 0, stream>>>((const int*)tok, (const int*)crd, (const int*)dna,
                                       (const int*)rna, (const int*)lig, (int*)(ws + 10));
  prep_kernel<<<LPTS / 256, 256, 0, stream>>>(XL, Xgt, crd, dna, rna, lig, tok, ws);
  pair_kernel<<<NPAIRTILES, 256, 0, stream>>>(ws);
  final_kernel<<<1, 1, 0, stream>>>(ws, t, out);
}

// Round 2
// 35.864 us; speedup vs baseline: 1.9242x; 1.9242x over previous
//
#include <hip/hip_runtime.h>

#define LPTS 4096
#define NTOKS 512
#define TILE 32
#define CAP (LPTS + TILE)               // compacted capacity incl. zero pad
#define NTMAX (CAP / TILE)              // 129
#define NBLK (NTMAX * (NTMAX + 1) / 2)  // 8385

// ws layout (bytes):
//   float[0..3]  mse_sum[4] (atomic)   float[4] mask_sum (atomic)
//   float[5..9]  fallback lddt accum (atomic, small-ws mode)
//   int[8..12]   format flags          int[16..31] per-chunk mask counts
//   int[32]      Lv (compacted count)
//   OFF_GT:  float4 cgt4[CAP] (gx,gy,gz,meta)   OFF_PX/PY/PZ: float4 pred coords (d=0..3)
//   OFF_PART: float partials[NBLK][5]
#define OFF_GT 256
#define OFF_PX (OFF_GT + CAP * 16)
#define OFF_PY (OFF_PX + CAP * 16)
#define OFF_PZ (OFF_PY + CAP * 16)
#define OFF_PART (OFF_PZ + CAP * 16)

static __device__ __forceinline__ float nan0(float x) {
  if (!(x == x)) return 0.f;
  return fminf(fmaxf(x, -3.402823466e38f), 3.402823466e38f);
}

// sigmoid(0.5-d)+sigmoid(1-d)+sigmoid(2-d)+sigmoid(4-d) = N(e)/D(e), e=exp(delta)
static __device__ __forceinline__ float sterm(float dx, float dy, float dz, float tmp) {
  float d2 = fmaf(dx, dx, fmaf(dy, dy, dz * dz));
  float pd = sqrtf(d2);
  float delta = fminf(fabsf(pd + tmp), 25.f);
  float e = __expf(delta);
  float e2 = e * e;
  float e3 = e2 * e;
  float e4 = e2 * e2;
  float Nn = fmaf(0.0366994762f, e3, fmaf(0.7506558488f, e2, fmaf(3.3841830690f, e, 4.f)));
  float Dd = fmaf(0.00055308437f, e4,
             fmaf(0.0366994762f, e3, fmaf(0.3753279244f, e2, fmaf(1.1280610231f, e, 1.f))));
  return Nn * __builtin_amdgcn_rcpf(Dd);
}

__global__ __launch_bounds__(256) void detect_count_kernel(
    const int* __restrict__ tok, const int* __restrict__ crd,
    const int* __restrict__ dna, const int* __restrict__ rna,
    const int* __restrict__ lig, int* __restrict__ wsi) {
  __shared__ int sflags[5];
  __shared__ int scount[256];
  int t = threadIdx.x;
  if (t < 5) sflags[t] = 0;
  __syncthreads();
  int f0 = 0;
  for (int i = t; i < LPTS / 2; i += 256)
    if (tok[2 * i + 1] != 0) f0 = 1;
  int f1 = 0;
  for (int i = t; i < LPTS / 4; i += 256)
    if ((unsigned)crd[i] > 1u) f1 = 1;
  int f2 = 0, f3 = 0, f4 = 0;
  for (int i = t; i < NTOKS / 4; i += 256) {
    if ((unsigned)dna[i] > 1u) f2 = 1;
    if ((unsigned)rna[i] > 1u) f3 = 1;
    if ((unsigned)lig[i] > 1u) f4 = 1;
  }
  if (f0) atomicOr(&sflags[0], 1);
  if (f1) atomicOr(&sflags[1], 1);
  if (f2) atomicOr(&sflags[2], 1);
  if (f3) atomicOr(&sflags[3], 1);
  if (f4) atomicOr(&sflags[4], 1);
  __syncthreads();
  bool crdb = sflags[1] != 0;
  int cnt = 0;
  for (int q = 0; q < 16; ++q) {
    int l = t * 16 + q;
    int m = (crdb ? (int)((const unsigned char*)crd)[l] : crd[l]) != 0;
    cnt += m;
  }
  scount[t] = cnt;
  __syncthreads();
  if (t < 16) {
    int s = 0;
    for (int q = 0; q < 16; ++q) s += scount[t * 16 + q];
    wsi[16 + t] = s;
  }
  if (t < 5) wsi[8 + t] = sflags[t];
}

__global__ __launch_bounds__(256) void prep_compact_kernel(
    const float* __restrict__ XL, const float* __restrict__ Xgt,
    const void* __restrict__ crd, const void* __restrict__ dna,
    const void* __restrict__ rna, const void* __restrict__ lig,
    const void* __restrict__ tok, float* __restrict__ ws) {
  int* wsi = (int*)ws;
  int b = blockIdx.x, t = threadIdx.x;
  int l = b * 256 + t;
  bool tok64 = wsi[8] == 0;
  bool crdb = wsi[9] != 0, dnab = wsi[10] != 0, rnab = wsi[11] != 0, ligb = wsi[12] != 0;
  int base = 0;
  for (int q = 0; q < b; ++q) base += wsi[16 + q];
  int tk = tok64 ? ((const int*)tok)[2 * l] : ((const int*)tok)[l];
  int tki = min(max(tk, 0), NTOKS - 1);
  int m  = (crdb ? (int)((const unsigned char*)crd)[l]   : ((const int*)crd)[l])   != 0;
  int dn = (dnab ? (int)((const unsigned char*)dna)[tki] : ((const int*)dna)[tki]) != 0;
  int rn = (rnab ? (int)((const unsigned char*)rna)[tki] : ((const int*)rna)[tki]) != 0;
  int lg = (ligb ? (int)((const unsigned char*)lig)[tki] : ((const int*)lig)[tki]) != 0;
  float w = (1.f + 5.f * dn + 5.f * rn + 10.f * lg) * (float)m;
  float gx = nan0(Xgt[3 * l + 0]);
  float gy = nan0(Xgt[3 * l + 1]);
  float gz = nan0(Xgt[3 * l + 2]);
  int isna = dn | rn;
  int meta = (tk & 0xFFFF) | (1 << 16) | (isna << 17);
  float xs[4], ys[4], zs[4];
  float v[5];
#pragma unroll
  for (int d = 0; d < 4; ++d) {
    xs[d] = XL[(d * LPTS + l) * 3 + 0];
    ys[d] = XL[(d * LPTS + l) * 3 + 1];
    zs[d] = XL[(d * LPTS + l) * 3 + 2];
    float dx = xs[d] - gx, dy = ys[d] - gy, dz = zs[d] - gz;
    v[d] = w * (dx * dx + dy * dy + dz * dz);
  }
  v[4] = (float)m;
  // ordered compaction position
  unsigned long long bal = __ballot(m);
  int lane = t & 63, wid = t >> 6;
  int pw = __popcll(bal & ((1ull << lane) - 1ull));
  __shared__ int wtot[4];
  if (lane == 0) wtot[wid] = __popcll(bal);
  __syncthreads();
  int wb = 0;
  for (int q = 0; q < wid; ++q) wb += wtot[q];
  int pos = base + wb + pw;
  float4* cgt4 = (float4*)((char*)ws + OFF_GT);
  float4* cpx  = (float4*)((char*)ws + OFF_PX);
  float4* cpy  = (float4*)((char*)ws + OFF_PY);
  float4* cpz  = (float4*)((char*)ws + OFF_PZ);
  if (m) {
    cgt4[pos] = make_float4(gx, gy, gz, __int_as_float(meta));
    cpx[pos] = make_float4(xs[0], xs[1], xs[2], xs[3]);
    cpy[pos] = make_float4(ys[0], ys[1], ys[2], ys[3]);
    cpz[pos] = make_float4(zs[0], zs[1], zs[2], zs[3]);
  }
  if (b == gridDim.x - 1) {  // last block: write Lv + zero padding
    int Lv = base + wtot[0] + wtot[1] + wtot[2] + wtot[3];
    if (t == 0) wsi[32] = Lv;
    if (t < TILE) {
      float4 z = make_float4(0.f, 0.f, 0.f, 0.f);
      cgt4[Lv + t] = z; cpx[Lv + t] = z; cpy[Lv + t] = z; cpz[Lv + t] = z;
    }
  }
  // MSE + mask-count reduction
#pragma unroll
  for (int k = 0; k < 5; ++k) {
    float x = v[k];
#pragma unroll
    for (int off = 32; off; off >>= 1) x += __shfl_down(x, off, 64);
    v[k] = x;
  }
  __shared__ float bred[4][5];
  if (lane == 0)
    for (int k = 0; k < 5; ++k) bred[wid][k] = v[k];
  __syncthreads();
  if (t == 0)
    for (int k = 0; k < 5; ++k)
      atomicAdd(&ws[k], bred[0][k] + bred[1][k] + bred[2][k] + bred[3][k]);
}

template <bool ATOMIC>
__global__ __launch_bounds__(256) void pair_kernel(float* __restrict__ ws) {
  const int* wsi = (const int*)ws;
  int Lv = wsi[32];
  int Lvp = (Lv + TILE - 1) & ~(TILE - 1);
  int NT = Lvp >> 5;
  int NA = NT * (NT + 1) / 2;
  int b = blockIdx.x;
  if (b >= NA) return;
  // b = tj*(tj+1)/2 + ti, ti <= tj  (active blocks contiguous)
  int tj = (int)((sqrtf(8.f * (float)b + 1.f) - 1.f) * 0.5f);
  while ((tj + 1) * (tj + 2) / 2 <= b) ++tj;
  while (tj * (tj + 1) / 2 > b) --tj;
  int ti = b - tj * (tj + 1) / 2;
  int i0 = ti * TILE, j0 = tj * TILE;

  const float4* cgt4 = (const float4*)((const char*)ws + OFF_GT);
  const float4* cpx  = (const float4*)((const char*)ws + OFF_PX);
  const float4* cpy  = (const float4*)((const char*)ws + OFF_PY);
  const float4* cpz  = (const float4*)((const char*)ws + OFF_PZ);
  __shared__ float4 sg[TILE], sx[TILE], sy[TILE], sz[TILE];
  int t = threadIdx.x;
  if (t < 32) sg[t] = cgt4[j0 + t];
  else if (t < 64) sx[t - 32] = cpx[j0 + t - 32];
  else if (t < 96) sy[t - 64] = cpy[j0 + t - 64];
  else if (t < 128) sz[t - 96] = cpz[j0 + t - 96];
  __syncthreads();

  int r = t & 31, g = t >> 5;
  int i = i0 + r;
  float4 rg = cgt4[i], rx = cpx[i], ry = cpy[i], rz = cpz[i];
  int rmeta = __float_as_int(rg.w);
  int rtok = rmeta & 0xFFFF;
  bool rm = (rmeta >> 16) & 1;
  float cutoff = ((rmeta >> 17) & 1) ? 30.f : 15.f;
  bool diag = (ti == tj);
  float4 accs = make_float4(0.f, 0.f, 0.f, 0.f);
  float accp = 0.f;
#pragma unroll
  for (int k = 0; k < 4; ++k) {
    int jj = g * 4 + k;
    float4 cg = sg[jj];
    int cmeta = __float_as_int(cg.w);
    float dgx = rg.x - cg.x, dgy = rg.y - cg.y, dgz = rg.z - cg.z;
    float gd = sqrtf(fmaf(dgx, dgx, fmaf(dgy, dgy, dgz * dgz)));
    bool pm = rm && ((cmeta >> 16) & 1) && (gd > 0.f) && (gd < cutoff) &&
              (rtok != (cmeta & 0xFFFF));
    if (diag) pm = pm && (j0 + jj > i);
    float pmf = pm ? 1.f : 0.f;
    float tmp = 1e-6f - gd;
    float4 cx = sx[jj], cy = sy[jj], cz = sz[jj];
    float s0 = sterm(rx.x - cx.x, ry.x - cy.x, rz.x - cz.x, tmp);
    float s1 = sterm(rx.y - cx.y, ry.y - cy.y, rz.y - cz.y, tmp);
    float s2 = sterm(rx.z - cx.z, ry.z - cy.z, rz.z - cz.z, tmp);
    float s3 = sterm(rx.w - cx.w, ry.w - cy.w, rz.w - cz.w, tmp);
    accs.x = fmaf(s0, pmf, accs.x);
    accs.y = fmaf(s1, pmf, accs.y);
    accs.z = fmaf(s2, pmf, accs.z);
    accs.w = fmaf(s3, pmf, accs.w);
    accp += pmf;
  }
  float v[5] = {accs.x, accs.y, accs.z, accs.w, accp};
#pragma unroll
  for (int k = 0; k < 5; ++k) {
    float x = v[k];
#pragma unroll
    for (int off = 32; off; off >>= 1) x += __shfl_down(x, off, 64);
    v[k] = x;
  }
  __shared__ float bred[4][5];
  int wid = t >> 6, lane = t & 63;
  if (lane == 0)
    for (int k = 0; k < 5; ++k) bred[wid][k] = v[k];
  __syncthreads();
  if (t == 0) {
    float* part = (float*)((char*)ws + OFF_PART);
    for (int k = 0; k < 5; ++k) {
      float s = bred[0][k] + bred[1][k] + bred[2][k] + bred[3][k];
      if (ATOMIC) atomicAdd(&ws[5 + k], s);
      else part[b * 5 + k] = s;
    }
  }
}

template <bool ATOMIC>
__global__ __launch_bounds__(256) void final_kernel(const float* __restrict__ ws,
                                                    const float* __restrict__ t_in,
                                                    float* __restrict__ out) {
  const int* wsi = (const int*)ws;
  int Lv = wsi[32];
  int Lvp = (Lv + TILE - 1) & ~(TILE - 1);
  int NT = Lvp >> 5;
  int NA = NT * (NT + 1) / 2;
  int t = threadIdx.x;
  float v[5] = {0.f, 0.f, 0.f, 0.f, 0.f};
  if (!ATOMIC) {
    const float* part = (const float*)((const char*)ws + OFF_PART);
    for (int i = t; i < NA; i += 256) {
      const float* p = part + i * 5;
#pragma unroll
      for (int k = 0; k < 5; ++k) v[k] += p[k];
    }
  } else if (t == 0) {
    for (int k = 0; k < 5; ++k) v[k] = ws[5 + k];
  }
#pragma unroll
  for (int k = 0; k < 5; ++k) {
    float x = v[k];
#pragma unroll
    for (int off = 32; off; off >>= 1) x += __shfl_down(x, off, 64);
    v[k] = x;
  }
  __shared__ float bred[4][5];
  int wid = t >> 6, lane = t & 63;
  if (lane == 0)
    for (int k = 0; k < 5; ++k) bred[wid][k] = v[k];
  __syncthreads();
  if (t == 0) {
    float ssum[4], pm_sum;
#pragma unroll
    for (int k = 0; k < 4; ++k) ssum[k] = bred[0][k] + bred[1][k] + bred[2][k] + bred[3][k];
    pm_sum = bred[0][4] + bred[1][4] + bred[2][4] + bred[3][4];
    float mask_sum = ws[4];
    float tot = 0.f;
#pragma unroll
    for (int d = 0; d < 4; ++d) {
      float lmse = (ws[d] * (1.f / 3.f)) / (mask_sum + 1e-4f);
      float td = t_in[d];
      float lam = (td * td + 256.f) / (256.f * td * td);
      float ldiff = fminf(lam * lmse, 2.f);
      float lddt = 0.25f * ssum[d] / (pm_sum + 1e-6f);
      tot += 0.25f * (ldiff + (1.f - lddt));
    }
    out[0] = 4.f * tot;
  }
}

extern "C" void kernel_launch(void* const* d_in, const int* in_sizes, int n_in,
                              void* d_out, int out_size, void* d_ws, size_t ws_size,
                              hipStream_t stream) {
  (void)in_sizes; (void)n_in; (void)out_size;
  const float* XL  = (const float*)d_in[0];
  const float* Xgt = (const float*)d_in[1];
  const void* crd  = d_in[2];
  const void* dna  = d_in[3];
  const void* rna  = d_in[4];
  const void* lig  = d_in[5];
  const void* tok  = d_in[6];
  const float* t   = (const float*)d_in[7];
  float* ws = (float*)d_ws;
  float* out = (float*)d_out;

  size_t needed = (size_t)OFF_PART + (size_t)NBLK * 5 * 4;
  bool small = ws_size < needed;

  hipMemsetAsync(d_ws, 0, 64, stream);  // zero atomic accumulators
  detect_count_kernel<<<1, 256, 0, stream>>>((const int*)tok, (const int*)crd,
                                             (const int*)dna, (const int*)rna,
                                             (const int*)lig, (int*)ws);
  prep_compact_kernel<<<16, 256, 0, stream>>>(XL, Xgt, crd, dna, rna, lig, tok, ws);
  if (small) {
    pair_kernel<true><<<NBLK, 256, 0, stream>>>(ws);
    final_kernel<true><<<1, 256, 0, stream>>>(ws, t, out);
  } else {
    pair_kernel<false><<<NBLK, 256, 0, stream>>>(ws);
    final_kernel<false><<<1, 256, 0, stream>>>(ws, t, out);
  }
}